// Round 1
// baseline (1527.221 us; speedup 1.0000x reference)
//
#include <hip/hip_runtime.h>
#include <math.h>

#define NN 10000
#define HIDD 256
#define MTOK 8
#define TT 3
#define EE 160000
#define AA 2000
#define OUTD 10
#define LNEPS 1e-5f

__device__ __forceinline__ float gelu_f(float x) {
    return 0.5f * x * (1.f + erff(x * 0.7071067811865475f));
}

// ---------------- graph build ----------------
__global__ void count_kernel(const int* __restrict__ dst, int* __restrict__ cnt) {
    int e = blockIdx.x * 256 + threadIdx.x;
    if (e < EE) atomicAdd(&cnt[dst[e]], 1);
}

__global__ __launch_bounds__(1024) void scan_kernel(const int* __restrict__ cnt,
        int* __restrict__ rowstart, int* __restrict__ cursor, float* __restrict__ dinv) {
    __shared__ int buf[1024];
    __shared__ int carry_s;
    int tid = threadIdx.x;
    if (tid == 0) carry_s = 0;
    __syncthreads();
    for (int base = 0; base < NN; base += 1024) {
        int i = base + tid;
        int v = (i < NN) ? cnt[i] : 0;
        buf[tid] = v;
        __syncthreads();
        for (int off = 1; off < 1024; off <<= 1) {
            int add = (tid >= off) ? buf[tid - off] : 0;
            __syncthreads();
            buf[tid] += add;
            __syncthreads();
        }
        int incl = buf[tid];
        int carry = carry_s;
        int tot = buf[1023];
        __syncthreads();
        if (i < NN) {
            int excl = carry + incl - v;
            rowstart[i] = excl;
            cursor[i] = excl;
            dinv[i] = rsqrtf((float)(v + 1));  // +1 self loop, always >=1
        }
        if (tid == 0) carry_s = carry + tot;
        __syncthreads();
    }
}

__global__ void fill_kernel(const int* __restrict__ src, const int* __restrict__ dst,
                            int* __restrict__ cursor, int* __restrict__ esrc) {
    int e = blockIdx.x * 256 + threadIdx.x;
    if (e < EE) {
        int d = dst[e];
        int idx = atomicAdd(&cursor[d], 1);
        esrc[idx] = src[e];
    }
}

// ---------------- generic [rows,256] @ [256,256] + bias + act ----------------
// ACT: 0 none, 1 relu, 2 tanh
template<int ACT>
__global__ __launch_bounds__(256) void gemm256(const float* __restrict__ A, const float* __restrict__ B,
        const float* __restrict__ bias, float* __restrict__ C, int rows) {
    __shared__ __align__(16) float sA[16][HIDD];
    int tid = threadIdx.x;
    int r0 = blockIdx.x * 16;
    #pragma unroll
    for (int m = 0; m < 16; m++) {
        int r = r0 + m;
        sA[m][tid] = (r < rows) ? A[(size_t)r * HIDD + tid] : 0.f;
    }
    __syncthreads();
    float acc[16];
    #pragma unroll
    for (int m = 0; m < 16; m++) acc[m] = 0.f;
    for (int h = 0; h < HIDD; h += 4) {
        float w0 = B[(h + 0) * HIDD + tid];
        float w1 = B[(h + 1) * HIDD + tid];
        float w2 = B[(h + 2) * HIDD + tid];
        float w3 = B[(h + 3) * HIDD + tid];
        #pragma unroll
        for (int m = 0; m < 16; m++) {
            const float4 a = *(const float4*)&sA[m][h];
            acc[m] = fmaf(a.x, w0, acc[m]);
            acc[m] = fmaf(a.y, w1, acc[m]);
            acc[m] = fmaf(a.z, w2, acc[m]);
            acc[m] = fmaf(a.w, w3, acc[m]);
        }
    }
    float bv = bias ? bias[tid] : 0.f;
    #pragma unroll
    for (int m = 0; m < 16; m++) {
        int r = r0 + m;
        if (r < rows) {
            float v = acc[m] + bv;
            if (ACT == 1) v = fmaxf(v, 0.f);
            if (ACT == 2) v = tanhf(v);
            C[(size_t)r * HIDD + tid] = v;
        }
    }
}

// ---------------- GCN aggregation (gather over dst-CSR) ----------------
__global__ __launch_bounds__(256) void gcn_agg(const float* __restrict__ xw, const int* __restrict__ esrc,
        const int* __restrict__ rowstart, const int* __restrict__ cnt, const float* __restrict__ dinv,
        const float* __restrict__ bias, float* __restrict__ out, int do_relu) {
    int wave = threadIdx.x >> 6, lane = threadIdx.x & 63;
    int d = blockIdx.x * 4 + wave;
    if (d >= NN) return;
    int start = rowstart[d];
    int len = cnt[d];
    float dd = dinv[d];
    int h = lane * 4;
    float4 a = *(const float4*)&xw[(size_t)d * HIDD + h];
    float4 acc;
    acc.x = a.x * dd; acc.y = a.y * dd; acc.z = a.z * dd; acc.w = a.w * dd;
    for (int i = 0; i < len; i++) {
        int s = esrc[start + i];
        float ds = dinv[s];
        float4 b = *(const float4*)&xw[(size_t)s * HIDD + h];
        acc.x = fmaf(b.x, ds, acc.x);
        acc.y = fmaf(b.y, ds, acc.y);
        acc.z = fmaf(b.z, ds, acc.z);
        acc.w = fmaf(b.w, ds, acc.w);
    }
    float o0 = acc.x * dd + bias[h + 0];
    float o1 = acc.y * dd + bias[h + 1];
    float o2 = acc.z * dd + bias[h + 2];
    float o3 = acc.w * dd + bias[h + 3];
    if (do_relu) {
        o0 = fmaxf(o0, 0.f); o1 = fmaxf(o1, 0.f); o2 = fmaxf(o2, 0.f); o3 = fmaxf(o3, 0.f);
    }
    float4 o; o.x = o0; o.y = o1; o.z = o2; o.w = o3;
    *(float4*)&out[(size_t)d * HIDD + h] = o;
}

__global__ void mask_kernel(const int* __restrict__ nid, float* __restrict__ x) {
    int node = nid[blockIdx.x];
    x[(size_t)node * HIDD + threadIdx.x] = 0.f;
}

__global__ void bcast_kernel(const float* __restrict__ row, float* __restrict__ out) {
    out[(size_t)blockIdx.x * HIDD + threadIdx.x] = row[threadIdx.x];
}

// ---------------- fused MLP-Mixer, one node per block ----------------
__global__ __launch_bounds__(256) void mixer_kernel(
        const float* __restrict__ prev1, const float* __restrict__ prev2,
        const float* __restrict__ ln1_g, const float* __restrict__ ln1_b,
        const float* __restrict__ tw1, const float* __restrict__ tb1,
        const float* __restrict__ tw2, const float* __restrict__ tb2,
        const float* __restrict__ ln2_g, const float* __restrict__ ln2_b,
        const float* __restrict__ cw1, const float* __restrict__ cb1,
        const float* __restrict__ cw2, const float* __restrict__ cb2,
        float* __restrict__ vout) {
    int n = blockIdx.x;
    int tid = threadIdx.x;
    int wave = tid >> 6, lane = tid & 63;
    __shared__ __align__(16) float sx[MTOK][HIDD];   // xm, then residual x
    __shared__ __align__(16) float sy[MTOK][HIDD];   // z / z2
    __shared__ float stw1[64], stw2[64], stb1[8], stb2[8];
    __shared__ float red[MTOK][2];
    if (tid < 64) { stw1[tid] = tw1[tid]; stw2[tid] = tw2[tid]; }
    if (tid < 8)  { stb1[tid] = tb1[tid]; stb2[tid] = tb2[tid]; }
    // window: token M-1 = x_{t-1}, token M-2 = x_{t-2}, rest zero
    #pragma unroll
    for (int m = 0; m < MTOK; m++) {
        const float* src = (m == MTOK - 1) ? prev1 : (m == MTOK - 2) ? prev2 : nullptr;
        sx[m][tid] = src ? src[(size_t)n * HIDD + tid] : 0.f;
    }
    __syncthreads();
    // ---- LN1 (into registers ty) ----
    float g1v = ln1_g[tid], b1v = ln1_b[tid];
    #pragma unroll
    for (int rep = 0; rep < 2; rep++) {
        int m = wave + rep * 4;
        float x0 = sx[m][lane], x1 = sx[m][lane + 64], x2 = sx[m][lane + 128], x3 = sx[m][lane + 192];
        float s = x0 + x1 + x2 + x3;
        float ss = x0 * x0 + x1 * x1 + x2 * x2 + x3 * x3;
        for (int off = 32; off > 0; off >>= 1) { s += __shfl_down(s, off, 64); ss += __shfl_down(ss, off, 64); }
        if (lane == 0) {
            float mu = s * (1.f / HIDD);
            float var = ss * (1.f / HIDD) - mu * mu;
            red[m][0] = mu;
            red[m][1] = rsqrtf(var + LNEPS);
        }
    }
    __syncthreads();
    float ty[MTOK];
    #pragma unroll
    for (int m = 0; m < MTOK; m++) ty[m] = (sx[m][tid] - red[m][0]) * red[m][1] * g1v + b1v;
    // ---- token mix 1 + gelu ----
    float u[MTOK];
    #pragma unroll
    for (int k = 0; k < MTOK; k++) {
        float a = stb1[k];
        #pragma unroll
        for (int m = 0; m < MTOK; m++) a = fmaf(ty[m], stw1[m * MTOK + k], a);
        u[k] = gelu_f(a);
    }
    // ---- token mix 2 + residual into sx ----
    #pragma unroll
    for (int k = 0; k < MTOK; k++) {
        float a = stb2[k];
        #pragma unroll
        for (int m = 0; m < MTOK; m++) a = fmaf(u[m], stw2[m * MTOK + k], a);
        sx[k][tid] += a;
    }
    __syncthreads();
    // ---- LN2: sx -> sy ----
    float g2v = ln2_g[tid], b2v = ln2_b[tid];
    #pragma unroll
    for (int rep = 0; rep < 2; rep++) {
        int m = wave + rep * 4;
        float x0 = sx[m][lane], x1 = sx[m][lane + 64], x2 = sx[m][lane + 128], x3 = sx[m][lane + 192];
        float s = x0 + x1 + x2 + x3;
        float ss = x0 * x0 + x1 * x1 + x2 * x2 + x3 * x3;
        for (int off = 32; off > 0; off >>= 1) { s += __shfl_down(s, off, 64); ss += __shfl_down(ss, off, 64); }
        if (lane == 0) {
            float mu = s * (1.f / HIDD);
            float var = ss * (1.f / HIDD) - mu * mu;
            red[m][0] = mu;
            red[m][1] = rsqrtf(var + LNEPS);
        }
    }
    __syncthreads();
    #pragma unroll
    for (int m = 0; m < MTOK; m++) sy[m][tid] = (sx[m][tid] - red[m][0]) * red[m][1] * g2v + b2v;
    __syncthreads();
    // ---- channel MLP 1: z2 = gelu(z @ cw1 + cb1) ----
    float acc[MTOK];
    #pragma unroll
    for (int m = 0; m < MTOK; m++) acc[m] = 0.f;
    for (int h = 0; h < HIDD; h += 4) {
        float w0 = cw1[(h + 0) * HIDD + tid];
        float w1 = cw1[(h + 1) * HIDD + tid];
        float w2 = cw1[(h + 2) * HIDD + tid];
        float w3 = cw1[(h + 3) * HIDD + tid];
        #pragma unroll
        for (int m = 0; m < MTOK; m++) {
            const float4 a = *(const float4*)&sy[m][h];
            acc[m] = fmaf(a.x, w0, acc[m]);
            acc[m] = fmaf(a.y, w1, acc[m]);
            acc[m] = fmaf(a.z, w2, acc[m]);
            acc[m] = fmaf(a.w, w3, acc[m]);
        }
    }
    __syncthreads();
    float cb1v = cb1[tid];
    #pragma unroll
    for (int m = 0; m < MTOK; m++) sy[m][tid] = gelu_f(acc[m] + cb1v);
    __syncthreads();
    // ---- channel MLP 2 + residual + token-mean ----
    float acc2[MTOK];
    #pragma unroll
    for (int m = 0; m < MTOK; m++) acc2[m] = 0.f;
    for (int h = 0; h < HIDD; h += 4) {
        float w0 = cw2[(h + 0) * HIDD + tid];
        float w1 = cw2[(h + 1) * HIDD + tid];
        float w2 = cw2[(h + 2) * HIDD + tid];
        float w3 = cw2[(h + 3) * HIDD + tid];
        #pragma unroll
        for (int m = 0; m < MTOK; m++) {
            const float4 a = *(const float4*)&sy[m][h];
            acc2[m] = fmaf(a.x, w0, acc2[m]);
            acc2[m] = fmaf(a.y, w1, acc2[m]);
            acc2[m] = fmaf(a.z, w2, acc2[m]);
            acc2[m] = fmaf(a.w, w3, acc2[m]);
        }
    }
    float cb2v = cb2[tid];
    float ssum = 0.f;
    #pragma unroll
    for (int m = 0; m < MTOK; m++) ssum += sx[m][tid] + acc2[m] + cb2v;
    vout[(size_t)n * HIDD + tid] = ssum * (1.f / MTOK);
}

// ---------------- final small head: y = relu(g1 @ cls2_w + cls2_b) ----------------
__global__ __launch_bounds__(256) void cls2_kernel(const float* __restrict__ g1, const float* __restrict__ w,
        const float* __restrict__ b, float* __restrict__ out, int rows) {
    __shared__ float sw[HIDD][12];
    int tid = threadIdx.x;
    for (int i = tid; i < HIDD * OUTD; i += 256) sw[i / OUTD][i % OUTD] = w[i];
    __syncthreads();
    int rl = tid >> 4, kk = tid & 15;
    int r = blockIdx.x * 16 + rl;
    if (r < rows && kk < OUTD) {
        float acc = 0.f;
        const float* grow = g1 + (size_t)r * HIDD;
        for (int h = 0; h < HIDD; h++) acc = fmaf(grow[h], sw[h][kk], acc);
        out[(size_t)r * OUTD + kk] = fmaxf(acc + b[kk], 0.f);
    }
}

extern "C" void kernel_launch(void* const* d_in, const int* in_sizes, int n_in,
                              void* d_out, int out_size, void* d_ws, size_t ws_size,
                              hipStream_t stream) {
    const int* edge    = (const int*)d_in[0];
    const int* node_t  = (const int*)d_in[1];
    const float* emb   = (const float*)d_in[3];
    const float* gcn_w1 = (const float*)d_in[4];
    const float* gcn_b1 = (const float*)d_in[5];
    const float* gcn_w2 = (const float*)d_in[6];
    const float* gcn_b2 = (const float*)d_in[7];
    const float* ln1_g = (const float*)d_in[8];
    const float* ln1_b = (const float*)d_in[9];
    const float* tw1   = (const float*)d_in[10];
    const float* tb1   = (const float*)d_in[11];
    const float* tw2   = (const float*)d_in[12];
    const float* tb2   = (const float*)d_in[13];
    const float* ln2_g = (const float*)d_in[14];
    const float* ln2_b = (const float*)d_in[15];
    const float* cw1   = (const float*)d_in[16];
    const float* cb1   = (const float*)d_in[17];
    const float* cw2   = (const float*)d_in[18];
    const float* cb2   = (const float*)d_in[19];
    const float* pred_w = (const float*)d_in[20];
    const float* pred_b = (const float*)d_in[21];
    const float* cls1_w = (const float*)d_in[22];
    const float* cls1_b = (const float*)d_in[23];
    const float* cls2_w = (const float*)d_in[24];
    const float* cls2_b = (const float*)d_in[25];

    float* ws    = (float*)d_ws;
    float* xs0   = ws;                    // [N,256]
    float* xs1   = ws + 2560000;          // [N,256]
    float* xw    = ws + 5120000;          // [N,256] scratch
    float* agg   = ws + 7680000;          // [N,256] scratch (also v_t temp)
    float* dinv  = ws + 10240000;         // [N]
    float* v0row = ws + 10250000;         // [256]
    int* ibase   = (int*)(ws + 10250496);
    int* cnt     = ibase;                 // [N]
    int* rowst   = ibase + 10000;         // [N]
    int* cursor  = ibase + 20000;         // [N]
    int* esrc    = ibase + 30000;         // [E]

    float* h_out = (float*)d_out;                    // [3*N*256]
    float* y_out = h_out + (size_t)TT * NN * HIDD;   // [3*N*10]
    float* g1    = ws;                               // head scratch, overlays xs0..xw

    float* xs_arr[2] = { xs0, xs1 };

    for (int t = 0; t < TT; t++) {
        const float* prev1 = (t >= 1) ? xs_arr[(t - 1) & 1] : nullptr;
        const float* prev2 = (t >= 2) ? xs_arr[(t - 2) & 1] : nullptr;
        // v_t -> agg
        if (t == 0) {
            // all nodes identical (zero window): compute once, broadcast
            mixer_kernel<<<1, 256, 0, stream>>>(nullptr, nullptr,
                ln1_g, ln1_b, tw1, tb1, tw2, tb2, ln2_g, ln2_b, cw1, cb1, cw2, cb2, v0row);
            bcast_kernel<<<NN, 256, 0, stream>>>(v0row, agg);
        } else {
            mixer_kernel<<<NN, 256, 0, stream>>>(prev1, prev2,
                ln1_g, ln1_b, tw1, tb1, tw2, tb2, ln2_g, ln2_b, cw1, cb1, cw2, cb2, agg);
        }
        // h_t = tanh(v_t @ pred_w + pred_b)
        gemm256<2><<<(NN + 15) / 16, 256, 0, stream>>>(agg, pred_w, pred_b,
                h_out + (size_t)t * NN * HIDD, NN);
        // GCN update (step 2's output is dead -> skip)
        if (t < TT - 1) {
            const int* src = edge + (size_t)t * 2 * EE;
            const int* dst = src + EE;
            hipMemsetAsync(cnt, 0, NN * sizeof(int), stream);
            count_kernel<<<(EE + 255) / 256, 256, 0, stream>>>(dst, cnt);
            scan_kernel<<<1, 1024, 0, stream>>>(cnt, rowst, cursor, dinv);
            fill_kernel<<<(EE + 255) / 256, 256, 0, stream>>>(src, dst, cursor, esrc);
            gemm256<0><<<(NN + 15) / 16, 256, 0, stream>>>(emb, gcn_w1, nullptr, xw, NN);
            gcn_agg<<<(NN + 3) / 4, 256, 0, stream>>>(xw, esrc, rowst, cnt, dinv, gcn_b1, agg, 1);
            gemm256<0><<<(NN + 15) / 16, 256, 0, stream>>>(agg, gcn_w2, nullptr, xw, NN);
            gcn_agg<<<(NN + 3) / 4, 256, 0, stream>>>(xw, esrc, rowst, cnt, dinv, gcn_b2, xs_arr[t & 1], 0);
            mask_kernel<<<AA, 256, 0, stream>>>(node_t + (size_t)t * AA, xs_arr[t & 1]);
        }
    }
    // head: g1 = h @ cls1_w + cls1_b ; y = relu(g1 @ cls2_w + cls2_b)
    gemm256<0><<<(TT * NN + 15) / 16, 256, 0, stream>>>(h_out, cls1_w, cls1_b, g1, TT * NN);
    cls2_kernel<<<(TT * NN + 15) / 16, 256, 0, stream>>>(g1, cls2_w, cls2_b, y_out, TT * NN);
}

// Round 2
// 1101.985 us; speedup vs baseline: 1.3859x; 1.3859x over previous
//
#include <hip/hip_runtime.h>
#include <math.h>

#define NN 10000
#define HIDD 256
#define MTOK 8
#define TT 3
#define EE 160000
#define AA 2000
#define OUTD 10
#define LNEPS 1e-5f
#define CHN 2560   // nodes per mixer chunk (multiple of 16)

typedef unsigned short u16;
typedef __attribute__((ext_vector_type(8))) __bf16 bf16x8;
typedef __attribute__((ext_vector_type(4))) float f32x4;

__device__ __forceinline__ float gelu_f(float x) {
    return 0.5f * x * (1.f + erff(x * 0.7071067811865475f));
}
__device__ __forceinline__ u16 f2bf(float x) {
    unsigned u = __builtin_bit_cast(unsigned, x);
    return (u16)((u + 0x7FFFu + ((u >> 16) & 1u)) >> 16);
}
__device__ __forceinline__ float bf2f(u16 b) {
    return __builtin_bit_cast(float, (unsigned)b << 16);
}

// ---------------- graph build ----------------
__global__ void count_kernel(const int* __restrict__ dst, int* __restrict__ cnt) {
    int e = blockIdx.x * 256 + threadIdx.x;
    if (e < EE) atomicAdd(&cnt[dst[e]], 1);
}

__global__ __launch_bounds__(1024) void scan_kernel(const int* __restrict__ cnt,
        int* __restrict__ rowstart, int* __restrict__ cursor, float* __restrict__ dinv) {
    __shared__ int buf[1024];
    __shared__ int carry_s;
    int tid = threadIdx.x;
    if (tid == 0) carry_s = 0;
    __syncthreads();
    for (int base = 0; base < NN; base += 1024) {
        int i = base + tid;
        int v = (i < NN) ? cnt[i] : 0;
        buf[tid] = v;
        __syncthreads();
        for (int off = 1; off < 1024; off <<= 1) {
            int add = (tid >= off) ? buf[tid - off] : 0;
            __syncthreads();
            buf[tid] += add;
            __syncthreads();
        }
        int incl = buf[tid];
        int carry = carry_s;
        int tot = buf[1023];
        __syncthreads();
        if (i < NN) {
            int excl = carry + incl - v;
            rowstart[i] = excl;
            cursor[i] = excl;
            dinv[i] = rsqrtf((float)(v + 1));
        }
        if (tid == 0) carry_s = carry + tot;
        __syncthreads();
    }
}

__global__ void fill_kernel(const int* __restrict__ src, const int* __restrict__ dst,
                            int* __restrict__ cursor, int* __restrict__ esrc) {
    int e = blockIdx.x * 256 + threadIdx.x;
    if (e < EE) {
        int d = dst[e];
        int idx = atomicAdd(&cursor[d], 1);
        esrc[idx] = src[e];
    }
}

// ---------------- f32 [rows,256] @ [256,256] (GCN only) ----------------
template<int ACT>
__global__ __launch_bounds__(256) void gemm256(const float* __restrict__ A, const float* __restrict__ B,
        const float* __restrict__ bias, float* __restrict__ C, int rows) {
    __shared__ __align__(16) float sA[16][HIDD];
    int tid = threadIdx.x;
    int r0 = blockIdx.x * 16;
    #pragma unroll
    for (int m = 0; m < 16; m++) {
        int r = r0 + m;
        sA[m][tid] = (r < rows) ? A[(size_t)r * HIDD + tid] : 0.f;
    }
    __syncthreads();
    float acc[16];
    #pragma unroll
    for (int m = 0; m < 16; m++) acc[m] = 0.f;
    for (int h = 0; h < HIDD; h += 4) {
        float w0 = B[(h + 0) * HIDD + tid];
        float w1 = B[(h + 1) * HIDD + tid];
        float w2 = B[(h + 2) * HIDD + tid];
        float w3 = B[(h + 3) * HIDD + tid];
        #pragma unroll
        for (int m = 0; m < 16; m++) {
            const float4 a = *(const float4*)&sA[m][h];
            acc[m] = fmaf(a.x, w0, acc[m]);
            acc[m] = fmaf(a.y, w1, acc[m]);
            acc[m] = fmaf(a.z, w2, acc[m]);
            acc[m] = fmaf(a.w, w3, acc[m]);
        }
    }
    float bv = bias ? bias[tid] : 0.f;
    #pragma unroll
    for (int m = 0; m < 16; m++) {
        int r = r0 + m;
        if (r < rows) {
            float v = acc[m] + bv;
            if (ACT == 1) v = fmaxf(v, 0.f);
            if (ACT == 2) v = tanhf(v);
            C[(size_t)r * HIDD + tid] = v;
        }
    }
}

// ---------------- GCN aggregation ----------------
__global__ __launch_bounds__(256) void gcn_agg(const float* __restrict__ xw, const int* __restrict__ esrc,
        const int* __restrict__ rowstart, const int* __restrict__ cnt, const float* __restrict__ dinv,
        const float* __restrict__ bias, float* __restrict__ out, int do_relu) {
    int wave = threadIdx.x >> 6, lane = threadIdx.x & 63;
    int d = blockIdx.x * 4 + wave;
    if (d >= NN) return;
    int start = rowstart[d];
    int len = cnt[d];
    float dd = dinv[d];
    int h = lane * 4;
    float4 a = *(const float4*)&xw[(size_t)d * HIDD + h];
    float4 acc;
    acc.x = a.x * dd; acc.y = a.y * dd; acc.z = a.z * dd; acc.w = a.w * dd;
    for (int i = 0; i < len; i++) {
        int s = esrc[start + i];
        float ds = dinv[s];
        float4 b = *(const float4*)&xw[(size_t)s * HIDD + h];
        acc.x = fmaf(b.x, ds, acc.x);
        acc.y = fmaf(b.y, ds, acc.y);
        acc.z = fmaf(b.z, ds, acc.z);
        acc.w = fmaf(b.w, ds, acc.w);
    }
    float o0 = acc.x * dd + bias[h + 0];
    float o1 = acc.y * dd + bias[h + 1];
    float o2 = acc.z * dd + bias[h + 2];
    float o3 = acc.w * dd + bias[h + 3];
    if (do_relu) {
        o0 = fmaxf(o0, 0.f); o1 = fmaxf(o1, 0.f); o2 = fmaxf(o2, 0.f); o3 = fmaxf(o3, 0.f);
    }
    float4 o; o.x = o0; o.y = o1; o.z = o2; o.w = o3;
    *(float4*)&out[(size_t)d * HIDD + h] = o;
}

__global__ void mask_kernel(const int* __restrict__ nid, float* __restrict__ x) {
    int node = nid[blockIdx.x];
    x[(size_t)node * HIDD + threadIdx.x] = 0.f;
}

__global__ void bcast_kernel(const float* __restrict__ row, float* __restrict__ out) {
    out[(size_t)blockIdx.x * HIDD + threadIdx.x] = row[threadIdx.x];
}

__global__ void bcast10_kernel(const float* __restrict__ y10, float* __restrict__ out) {
    int i = blockIdx.x * 256 + threadIdx.x;
    if (i < NN * OUTD) out[i] = y10[i % OUTD];
}

// ---------------- weight split+transpose+duplicate: W[256,256] -> Bt[256][768] ----------------
__global__ void wsplit_kernel(const float* __restrict__ Wm, u16* __restrict__ Bt) {
    int c = blockIdx.x, k = threadIdx.x;
    float x = Wm[k * 256 + c];
    u16 hi = f2bf(x), lo = f2bf(x - bf2f(hi));
    Bt[c * 768 + k] = hi;
    Bt[c * 768 + 256 + k] = hi;
    Bt[c * 768 + 512 + k] = lo;
}

// ---------------- split-bf16 MFMA GEMM: [R,256(hi)+256(lo)] x Bt[256][768] ----------------
// ACT: 0 none, 1 gelu, 2 tanh. MEAN: fused per-node (8-row) mean epilogue -> split out.
template<int ACT, int WF32, int WSPLIT, int MEAN>
__global__ __launch_bounds__(256) void gemm_split(
        const u16* __restrict__ Ahi, const u16* __restrict__ Alo,
        const u16* __restrict__ Bt, const float* __restrict__ bias,
        float* __restrict__ outf, u16* __restrict__ ohi, u16* __restrict__ olo,
        const float* __restrict__ xsum, int R) {
    __shared__ __align__(16) u16 ldsA[128 * 64];
    __shared__ __align__(16) u16 ldsB[128 * 64];
    int tid = threadIdx.x;
    int lane = tid & 63, w = tid >> 6;
    int rowbase = blockIdx.x * 128;
    int cb = blockIdx.y;
    int wrow = (w >> 1) * 64, wcol = (w & 1) * 64;
    f32x4 acc[4][4];
    #pragma unroll
    for (int i = 0; i < 4; i++)
        #pragma unroll
        for (int j = 0; j < 4; j++) acc[i][j] = f32x4{0.f, 0.f, 0.f, 0.f};

    for (int c = 0; c < 12; c++) {
        const u16* Aseg = (c >= 4 && c < 8) ? Alo : Ahi;
        int koff = (c & 3) * 64;
        __syncthreads();
        #pragma unroll
        for (int i = 0; i < 4; i++) {
            int j = i * 256 + tid;
            int r = j >> 3, sl = j & 7;
            int grow = rowbase + r; if (grow > R - 1) grow = R - 1;
            const u16* gp = Aseg + (size_t)grow * 256 + koff + ((sl ^ (r & 7)) << 3);
            *(uint4*)&ldsA[j << 3] = *(const uint4*)gp;
        }
        #pragma unroll
        for (int i = 0; i < 4; i++) {
            int j = i * 256 + tid;
            int r = j >> 3, sl = j & 7;
            const u16* gp = Bt + (size_t)(cb * 128 + r) * 768 + c * 64 + ((sl ^ (r & 7)) << 3);
            *(uint4*)&ldsB[j << 3] = *(const uint4*)gp;
        }
        __syncthreads();
        #pragma unroll
        for (int ks = 0; ks < 2; ks++) {
            bf16x8 a[4], b[4];
            #pragma unroll
            for (int rf = 0; rf < 4; rf++) {
                int rr = wrow + rf * 16 + (lane & 15);
                int slot = (lane >> 4) + ks * 4;
                a[rf] = *(const bf16x8*)&ldsA[(rr << 6) + ((slot ^ (rr & 7)) << 3)];
            }
            #pragma unroll
            for (int cf = 0; cf < 4; cf++) {
                int cc = wcol + cf * 16 + (lane & 15);
                int slot = (lane >> 4) + ks * 4;
                b[cf] = *(const bf16x8*)&ldsB[(cc << 6) + ((slot ^ (cc & 7)) << 3)];
            }
            #pragma unroll
            for (int rf = 0; rf < 4; rf++)
                #pragma unroll
                for (int cf = 0; cf < 4; cf++)
                    acc[rf][cf] = __builtin_amdgcn_mfma_f32_16x16x32_bf16(a[rf], b[cf], acc[rf][cf], 0, 0, 0);
        }
    }
    #pragma unroll
    for (int rf = 0; rf < 4; rf++) {
        #pragma unroll
        for (int cf = 0; cf < 4; cf++) {
            int col = cb * 128 + wcol + cf * 16 + (lane & 15);
            float bv = bias[col];
            f32x4 v = acc[rf][cf];
            if (MEAN) {
                float s = v[0] + v[1] + v[2] + v[3] + 4.f * bv;
                float o = __shfl_xor(s, 16, 64);
                float nodesum = s + o;
                if (((lane >> 4) & 1) == 0) {
                    int node = ((rowbase + wrow + rf * 16) >> 3) + ((lane >> 4) >> 1);
                    float vv = (xsum[(size_t)node * 256 + col] + nodesum) * 0.125f;
                    u16 hi = f2bf(vv), lo = f2bf(vv - bf2f(hi));
                    ohi[(size_t)node * 256 + col] = hi;
                    olo[(size_t)node * 256 + col] = lo;
                }
            } else {
                int row0 = rowbase + wrow + rf * 16 + ((lane >> 4) << 2);
                #pragma unroll
                for (int r = 0; r < 4; r++) {
                    int row = row0 + r;
                    if (row < R) {
                        float val = v[r] + bv;
                        if (ACT == 1) val = gelu_f(val);
                        if (ACT == 2) val = tanhf(val);
                        if (WF32) outf[(size_t)row * 256 + col] = val;
                        if (WSPLIT) {
                            u16 hi = f2bf(val), lo = f2bf(val - bf2f(hi));
                            ohi[(size_t)row * 256 + col] = hi;
                            olo[(size_t)row * 256 + col] = lo;
                        }
                    }
                }
            }
        }
    }
}

// ---------------- mixer front: window build, LN1, token-mix, residual, LN2, split ----------------
__global__ __launch_bounds__(256) void mixer_front(
        const float* __restrict__ prev1, const float* __restrict__ prev2, int nodebase,
        const float* __restrict__ ln1_g, const float* __restrict__ ln1_b,
        const float* __restrict__ tw1, const float* __restrict__ tb1,
        const float* __restrict__ tw2, const float* __restrict__ tb2,
        const float* __restrict__ ln2_g, const float* __restrict__ ln2_b,
        u16* __restrict__ z_hi, u16* __restrict__ z_lo, float* __restrict__ xsum_out) {
    int n = nodebase + blockIdx.x;
    int tid = threadIdx.x;
    int wave = tid >> 6, lane = tid & 63;
    __shared__ __align__(16) float sx[MTOK][HIDD];
    __shared__ float stw1[64], stw2[64], stb1[8], stb2[8];
    __shared__ float red[MTOK][2];
    if (tid < 64) { stw1[tid] = tw1[tid]; stw2[tid] = tw2[tid]; }
    if (tid < 8)  { stb1[tid] = tb1[tid]; stb2[tid] = tb2[tid]; }
    #pragma unroll
    for (int m = 0; m < MTOK; m++) {
        const float* src = (m == MTOK - 1) ? prev1 : (m == MTOK - 2) ? prev2 : nullptr;
        sx[m][tid] = src ? src[(size_t)n * HIDD + tid] : 0.f;
    }
    __syncthreads();
    float g1v = ln1_g[tid], b1v = ln1_b[tid];
    #pragma unroll
    for (int rep = 0; rep < 2; rep++) {
        int m = wave + rep * 4;
        float x0 = sx[m][lane], x1 = sx[m][lane + 64], x2 = sx[m][lane + 128], x3 = sx[m][lane + 192];
        float s = x0 + x1 + x2 + x3;
        float ss = x0 * x0 + x1 * x1 + x2 * x2 + x3 * x3;
        for (int off = 32; off > 0; off >>= 1) { s += __shfl_down(s, off, 64); ss += __shfl_down(ss, off, 64); }
        if (lane == 0) {
            float mu = s * (1.f / HIDD);
            float var = ss * (1.f / HIDD) - mu * mu;
            red[m][0] = mu;
            red[m][1] = rsqrtf(var + LNEPS);
        }
    }
    __syncthreads();
    float ty[MTOK];
    #pragma unroll
    for (int m = 0; m < MTOK; m++) ty[m] = (sx[m][tid] - red[m][0]) * red[m][1] * g1v + b1v;
    float u[MTOK];
    #pragma unroll
    for (int k = 0; k < MTOK; k++) {
        float a = stb1[k];
        #pragma unroll
        for (int m = 0; m < MTOK; m++) a = fmaf(ty[m], stw1[m * MTOK + k], a);
        u[k] = gelu_f(a);
    }
    #pragma unroll
    for (int k = 0; k < MTOK; k++) {
        float a = stb2[k];
        #pragma unroll
        for (int m = 0; m < MTOK; m++) a = fmaf(u[m], stw2[m * MTOK + k], a);
        sx[k][tid] += a;
    }
    __syncthreads();
    // residual sum over tokens
    float xs = 0.f;
    #pragma unroll
    for (int m = 0; m < MTOK; m++) xs += sx[m][tid];
    xsum_out[(size_t)n * HIDD + tid] = xs;
    // LN2 -> split bf16
    float g2v = ln2_g[tid], b2v = ln2_b[tid];
    #pragma unroll
    for (int rep = 0; rep < 2; rep++) {
        int m = wave + rep * 4;
        float x0 = sx[m][lane], x1 = sx[m][lane + 64], x2 = sx[m][lane + 128], x3 = sx[m][lane + 192];
        float s = x0 + x1 + x2 + x3;
        float ss = x0 * x0 + x1 * x1 + x2 * x2 + x3 * x3;
        for (int off = 32; off > 0; off >>= 1) { s += __shfl_down(s, off, 64); ss += __shfl_down(ss, off, 64); }
        if (lane == 0) {
            float mu = s * (1.f / HIDD);
            float var = ss * (1.f / HIDD) - mu * mu;
            red[m][0] = mu;
            red[m][1] = rsqrtf(var + LNEPS);
        }
    }
    __syncthreads();
    #pragma unroll
    for (int m = 0; m < MTOK; m++) {
        float z = (sx[m][tid] - red[m][0]) * red[m][1] * g2v + b2v;
        u16 hi = f2bf(z), lo = f2bf(z - bf2f(hi));
        size_t idx = ((size_t)blockIdx.x * MTOK + m) * HIDD + tid;
        z_hi[idx] = hi;
        z_lo[idx] = lo;
    }
}

// ---------------- full f32 mixer for the (uniform) t=0 row ----------------
__global__ __launch_bounds__(256) void mixer_kernel(
        const float* __restrict__ ln1_g, const float* __restrict__ ln1_b,
        const float* __restrict__ tw1, const float* __restrict__ tb1,
        const float* __restrict__ tw2, const float* __restrict__ tb2,
        const float* __restrict__ ln2_g, const float* __restrict__ ln2_b,
        const float* __restrict__ cw1, const float* __restrict__ cb1,
        const float* __restrict__ cw2, const float* __restrict__ cb2,
        float* __restrict__ vout) {
    int tid = threadIdx.x;
    __shared__ __align__(16) float sx[MTOK][HIDD];
    __shared__ __align__(16) float sy[MTOK][HIDD];
    __shared__ float stw1[64], stw2[64], stb1[8], stb2[8];
    if (tid < 64) { stw1[tid] = tw1[tid]; stw2[tid] = tw2[tid]; }
    if (tid < 8)  { stb1[tid] = tb1[tid]; stb2[tid] = tb2[tid]; }
    __syncthreads();
    // all-zero window: LN1 output = b1; token mixes
    float b1v = ln1_b[tid];
    float ty[MTOK];
    #pragma unroll
    for (int m = 0; m < MTOK; m++) ty[m] = b1v;
    float u[MTOK];
    #pragma unroll
    for (int k = 0; k < MTOK; k++) {
        float a = stb1[k];
        #pragma unroll
        for (int m = 0; m < MTOK; m++) a = fmaf(ty[m], stw1[m * MTOK + k], a);
        u[k] = gelu_f(a);
    }
    #pragma unroll
    for (int k = 0; k < MTOK; k++) {
        float a = stb2[k];
        #pragma unroll
        for (int m = 0; m < MTOK; m++) a = fmaf(u[m], stw2[m * MTOK + k], a);
        sx[k][tid] = a;   // x = 0 + y
    }
    __syncthreads();
    // LN2
    __shared__ float red[MTOK][2];
    int wave = tid >> 6, lane = tid & 63;
    float g2v = ln2_g[tid], b2v = ln2_b[tid];
    #pragma unroll
    for (int rep = 0; rep < 2; rep++) {
        int m = wave + rep * 4;
        float x0 = sx[m][lane], x1 = sx[m][lane + 64], x2 = sx[m][lane + 128], x3 = sx[m][lane + 192];
        float s = x0 + x1 + x2 + x3;
        float ss = x0 * x0 + x1 * x1 + x2 * x2 + x3 * x3;
        for (int off = 32; off > 0; off >>= 1) { s += __shfl_down(s, off, 64); ss += __shfl_down(ss, off, 64); }
        if (lane == 0) {
            float mu = s * (1.f / HIDD);
            float var = ss * (1.f / HIDD) - mu * mu;
            red[m][0] = mu;
            red[m][1] = rsqrtf(var + LNEPS);
        }
    }
    __syncthreads();
    #pragma unroll
    for (int m = 0; m < MTOK; m++) sy[m][tid] = (sx[m][tid] - red[m][0]) * red[m][1] * g2v + b2v;
    __syncthreads();
    float acc[MTOK];
    #pragma unroll
    for (int m = 0; m < MTOK; m++) acc[m] = 0.f;
    for (int h = 0; h < HIDD; h += 4) {
        float w0 = cw1[(h + 0) * HIDD + tid];
        float w1 = cw1[(h + 1) * HIDD + tid];
        float w2 = cw1[(h + 2) * HIDD + tid];
        float w3 = cw1[(h + 3) * HIDD + tid];
        #pragma unroll
        for (int m = 0; m < MTOK; m++) {
            const float4 a = *(const float4*)&sy[m][h];
            acc[m] = fmaf(a.x, w0, acc[m]);
            acc[m] = fmaf(a.y, w1, acc[m]);
            acc[m] = fmaf(a.z, w2, acc[m]);
            acc[m] = fmaf(a.w, w3, acc[m]);
        }
    }
    __syncthreads();
    float cb1v = cb1[tid];
    #pragma unroll
    for (int m = 0; m < MTOK; m++) sy[m][tid] = gelu_f(acc[m] + cb1v);
    __syncthreads();
    float acc2[MTOK];
    #pragma unroll
    for (int m = 0; m < MTOK; m++) acc2[m] = 0.f;
    for (int h = 0; h < HIDD; h += 4) {
        float w0 = cw2[(h + 0) * HIDD + tid];
        float w1 = cw2[(h + 1) * HIDD + tid];
        float w2 = cw2[(h + 2) * HIDD + tid];
        float w3 = cw2[(h + 3) * HIDD + tid];
        #pragma unroll
        for (int m = 0; m < MTOK; m++) {
            const float4 a = *(const float4*)&sy[m][h];
            acc2[m] = fmaf(a.x, w0, acc2[m]);
            acc2[m] = fmaf(a.y, w1, acc2[m]);
            acc2[m] = fmaf(a.z, w2, acc2[m]);
            acc2[m] = fmaf(a.w, w3, acc2[m]);
        }
    }
    float cb2v = cb2[tid];
    float ssum = 0.f;
    #pragma unroll
    for (int m = 0; m < MTOK; m++) ssum += sx[m][tid] + acc2[m] + cb2v;
    vout[tid] = ssum * (1.f / MTOK);
}

// ---------------- single-row head kernels (t=0 path) ----------------
template<int ACT>
__global__ __launch_bounds__(256) void rowgemm_kernel(const float* __restrict__ in_row,
        const float* __restrict__ Wm, const float* __restrict__ b, float* __restrict__ out_row) {
    __shared__ float s[HIDD];
    int tid = threadIdx.x;
    s[tid] = in_row[tid];
    __syncthreads();
    float acc = 0.f;
    for (int k = 0; k < HIDD; k++) acc = fmaf(s[k], Wm[k * HIDD + tid], acc);
    float v = acc + b[tid];
    if (ACT == 2) v = tanhf(v);
    out_row[tid] = v;
}

__global__ __launch_bounds__(256) void rowcls2_kernel(const float* __restrict__ g1row,
        const float* __restrict__ wm, const float* __restrict__ b, float* __restrict__ y10) {
    __shared__ float s[HIDD];
    int tid = threadIdx.x;
    s[tid] = g1row[tid];
    __syncthreads();
    if (tid < OUTD) {
        float a = 0.f;
        for (int h = 0; h < HIDD; h++) a = fmaf(s[h], wm[h * OUTD + tid], a);
        y10[tid] = fmaxf(a + b[tid], 0.f);
    }
}

// ---------------- cls2 for the big rows ----------------
__global__ __launch_bounds__(256) void cls2_kernel(const float* __restrict__ g1, const float* __restrict__ wm,
        const float* __restrict__ b, float* __restrict__ out, int rows) {
    __shared__ float sw[HIDD][12];
    int tid = threadIdx.x;
    for (int i = tid; i < HIDD * OUTD; i += 256) sw[i / OUTD][i % OUTD] = wm[i];
    __syncthreads();
    int rl = tid >> 4, kk = tid & 15;
    int r = blockIdx.x * 16 + rl;
    if (r < rows && kk < OUTD) {
        float acc = 0.f;
        const float* grow = g1 + (size_t)r * HIDD;
        for (int h = 0; h < HIDD; h++) acc = fmaf(grow[h], sw[h][kk], acc);
        out[(size_t)r * OUTD + kk] = fmaxf(acc + b[kk], 0.f);
    }
}

extern "C" void kernel_launch(void* const* d_in, const int* in_sizes, int n_in,
                              void* d_out, int out_size, void* d_ws, size_t ws_size,
                              hipStream_t stream) {
    const int* edge    = (const int*)d_in[0];
    const int* node_t  = (const int*)d_in[1];
    const float* emb   = (const float*)d_in[3];
    const float* gcn_w1 = (const float*)d_in[4];
    const float* gcn_b1 = (const float*)d_in[5];
    const float* gcn_w2 = (const float*)d_in[6];
    const float* gcn_b2 = (const float*)d_in[7];
    const float* ln1_g = (const float*)d_in[8];
    const float* ln1_b = (const float*)d_in[9];
    const float* tw1   = (const float*)d_in[10];
    const float* tb1   = (const float*)d_in[11];
    const float* tw2   = (const float*)d_in[12];
    const float* tb2   = (const float*)d_in[13];
    const float* ln2_g = (const float*)d_in[14];
    const float* ln2_b = (const float*)d_in[15];
    const float* cw1   = (const float*)d_in[16];
    const float* cb1   = (const float*)d_in[17];
    const float* cw2   = (const float*)d_in[18];
    const float* cb2   = (const float*)d_in[19];
    const float* pred_w = (const float*)d_in[20];
    const float* pred_b = (const float*)d_in[21];
    const float* cls1_w = (const float*)d_in[22];
    const float* cls1_b = (const float*)d_in[23];
    const float* cls2_w = (const float*)d_in[24];
    const float* cls2_b = (const float*)d_in[25];

    char* wsb = (char*)d_ws;
    size_t off = 0;
    auto alloc = [&](size_t bytes) { char* p = wsb + off; off = (off + bytes + 255) & ~(size_t)255; return p; };
    const size_t ZE = (size_t)CHN * MTOK * HIDD;           // chunk z elements
    u16* z_hi  = (u16*)alloc(ZE * 2);
    u16* z_lo  = (u16*)alloc(ZE * 2);
    u16* z2_hi = (u16*)alloc(ZE * 2);
    u16* z2_lo = (u16*)alloc(ZE * 2);
    float* xsum = (float*)alloc((size_t)NN * HIDD * 4);
    u16* v_hi  = (u16*)alloc((size_t)NN * HIDD * 2);
    u16* v_lo  = (u16*)alloc((size_t)NN * HIDD * 2);
    u16* h_hi  = (u16*)alloc((size_t)2 * NN * HIDD * 2);
    u16* h_lo  = (u16*)alloc((size_t)2 * NN * HIDD * 2);
    float* g1  = (float*)alloc((size_t)2 * NN * HIDD * 4);
    float* xs0 = (float*)alloc((size_t)NN * HIDD * 4);
    float* xs1 = (float*)alloc((size_t)NN * HIDD * 4);
    float* xw  = (float*)alloc((size_t)NN * HIDD * 4);
    float* agg = (float*)alloc((size_t)NN * HIDD * 4);
    u16* Bt_cw1  = (u16*)alloc(256 * 768 * 2);
    u16* Bt_cw2  = (u16*)alloc(256 * 768 * 2);
    u16* Bt_pred = (u16*)alloc(256 * 768 * 2);
    u16* Bt_cls1 = (u16*)alloc(256 * 768 * 2);
    float* dinv  = (float*)alloc(NN * 4);
    float* v0row = (float*)alloc(HIDD * 4);
    float* h0row = (float*)alloc(HIDD * 4);
    float* g1row = (float*)alloc(HIDD * 4);
    float* y0row = (float*)alloc(16 * 4);
    int* cnt    = (int*)alloc(NN * 4);
    int* rowst  = (int*)alloc(NN * 4);
    int* cursor = (int*)alloc(NN * 4);
    int* esrc   = (int*)alloc(EE * 4);

    float* h_out = (float*)d_out;                    // [3*N*256]
    float* y_out = h_out + (size_t)TT * NN * HIDD;   // [3*N*10]

    float* xs_arr[2] = { xs0, xs1 };

    // weight splits
    wsplit_kernel<<<256, 256, 0, stream>>>(cw1, Bt_cw1);
    wsplit_kernel<<<256, 256, 0, stream>>>(cw2, Bt_cw2);
    wsplit_kernel<<<256, 256, 0, stream>>>(pred_w, Bt_pred);
    wsplit_kernel<<<256, 256, 0, stream>>>(cls1_w, Bt_cls1);

    for (int t = 0; t < TT; t++) {
        if (t == 0) {
            // all nodes identical at t=0: single-row path + broadcast
            mixer_kernel<<<1, 256, 0, stream>>>(ln1_g, ln1_b, tw1, tb1, tw2, tb2,
                ln2_g, ln2_b, cw1, cb1, cw2, cb2, v0row);
            rowgemm_kernel<2><<<1, 256, 0, stream>>>(v0row, pred_w, pred_b, h0row);
            bcast_kernel<<<NN, 256, 0, stream>>>(h0row, h_out);
            rowgemm_kernel<0><<<1, 256, 0, stream>>>(h0row, cls1_w, cls1_b, g1row);
            rowcls2_kernel<<<1, 256, 0, stream>>>(g1row, cls2_w, cls2_b, y0row);
            bcast10_kernel<<<(NN * OUTD + 255) / 256, 256, 0, stream>>>(y0row, y_out);
        } else {
            const float* prev1 = xs_arr[(t - 1) & 1];
            const float* prev2 = (t >= 2) ? xs_arr[(t - 2) & 1] : nullptr;
            for (int nb = 0; nb < NN; nb += CHN) {
                int nodes = NN - nb < CHN ? NN - nb : CHN;
                int R = nodes * MTOK;
                int rb = R / 128;
                mixer_front<<<nodes, 256, 0, stream>>>(prev1, prev2, nb,
                    ln1_g, ln1_b, tw1, tb1, tw2, tb2, ln2_g, ln2_b, z_hi, z_lo, xsum);
                gemm_split<1, 0, 1, 0><<<dim3(rb, 2), 256, 0, stream>>>(
                    z_hi, z_lo, Bt_cw1, cb1, nullptr, z2_hi, z2_lo, nullptr, R);
                gemm_split<0, 0, 1, 1><<<dim3(rb, 2), 256, 0, stream>>>(
                    z2_hi, z2_lo, Bt_cw2, cb2, nullptr,
                    v_hi + (size_t)nb * HIDD, v_lo + (size_t)nb * HIDD,
                    xsum + (size_t)nb * HIDD, R);
            }
            gemm_split<2, 1, 1, 0><<<dim3((NN + 127) / 128, 2), 256, 0, stream>>>(
                v_hi, v_lo, Bt_pred, pred_b,
                h_out + (size_t)t * NN * HIDD,
                h_hi + (size_t)(t - 1) * NN * HIDD, h_lo + (size_t)(t - 1) * NN * HIDD, nullptr, NN);
        }
        if (t < TT - 1) {
            const int* src = edge + (size_t)t * 2 * EE;
            const int* dst = src + EE;
            hipMemsetAsync(cnt, 0, NN * sizeof(int), stream);
            count_kernel<<<(EE + 255) / 256, 256, 0, stream>>>(dst, cnt);
            scan_kernel<<<1, 1024, 0, stream>>>(cnt, rowst, cursor, dinv);
            fill_kernel<<<(EE + 255) / 256, 256, 0, stream>>>(src, dst, cursor, esrc);
            gemm256<0><<<(NN + 15) / 16, 256, 0, stream>>>(emb, gcn_w1, nullptr, xw, NN);
            gcn_agg<<<(NN + 3) / 4, 256, 0, stream>>>(xw, esrc, rowst, cnt, dinv, gcn_b1, agg, 1);
            gemm256<0><<<(NN + 15) / 16, 256, 0, stream>>>(agg, gcn_w2, nullptr, xw, NN);
            gcn_agg<<<(NN + 3) / 4, 256, 0, stream>>>(xw, esrc, rowst, cnt, dinv, gcn_b2, xs_arr[t & 1], 0);
            mask_kernel<<<AA, 256, 0, stream>>>(node_t + (size_t)t * AA, xs_arr[t & 1]);
        }
    }
    // head for t=1,2 rows
    gemm_split<0, 1, 0, 0><<<dim3((2 * NN + 127) / 128, 2), 256, 0, stream>>>(
        h_hi, h_lo, Bt_cls1, cls1_b, g1, nullptr, nullptr, nullptr, 2 * NN);
    cls2_kernel<<<(2 * NN + 15) / 16, 256, 0, stream>>>(g1, cls2_w, cls2_b, y_out + (size_t)NN * OUTD, 2 * NN);
}

// Round 4
// 986.317 us; speedup vs baseline: 1.5484x; 1.1173x over previous
//
#include <hip/hip_runtime.h>
#include <math.h>

#define NN 10000
#define HIDD 256
#define MTOK 8
#define TT 3
#define EE 160000
#define AA 2000
#define OUTD 10
#define LNEPS 1e-5f

typedef unsigned short u16;
typedef __attribute__((ext_vector_type(8))) __bf16 bf16x8;
typedef __attribute__((ext_vector_type(4))) float f32x4;

__device__ __forceinline__ float gelu_f(float x) {
    return 0.5f * x * (1.f + erff(x * 0.7071067811865475f));
}
__device__ __forceinline__ u16 f2bf(float x) {
    unsigned u = __builtin_bit_cast(unsigned, x);
    return (u16)((u + 0x7FFFu + ((u >> 16) & 1u)) >> 16);
}
__device__ __forceinline__ float bf2f(u16 b) {
    return __builtin_bit_cast(float, (unsigned)b << 16);
}
__device__ __forceinline__ void gload16(const void* g, void* l) {
    __builtin_amdgcn_global_load_lds(
        (const __attribute__((address_space(1))) unsigned int*)g,
        (__attribute__((address_space(3))) unsigned int*)l, 16, 0, 0);
}

// ---------------- graph build ----------------
__global__ void count_kernel(const int* __restrict__ dst, int* __restrict__ cnt) {
    int e = blockIdx.x * 256 + threadIdx.x;
    if (e < EE) atomicAdd(&cnt[dst[e]], 1);
}

__global__ __launch_bounds__(1024) void scan_kernel(const int* __restrict__ cnt,
        int* __restrict__ rowstart, int* __restrict__ cursor, float* __restrict__ dinv) {
    __shared__ int buf[1024];
    __shared__ int carry_s;
    int tid = threadIdx.x;
    if (tid == 0) carry_s = 0;
    __syncthreads();
    for (int base = 0; base < NN; base += 1024) {
        int i = base + tid;
        int v = (i < NN) ? cnt[i] : 0;
        buf[tid] = v;
        __syncthreads();
        for (int off = 1; off < 1024; off <<= 1) {
            int add = (tid >= off) ? buf[tid - off] : 0;
            __syncthreads();
            buf[tid] += add;
            __syncthreads();
        }
        int incl = buf[tid];
        int carry = carry_s;
        int tot = buf[1023];
        __syncthreads();
        if (i < NN) {
            int excl = carry + incl - v;
            rowstart[i] = excl;
            cursor[i] = excl;
            dinv[i] = rsqrtf((float)(v + 1));
        }
        if (tid == 0) carry_s = carry + tot;
        __syncthreads();
    }
}

__global__ void fill_kernel(const int* __restrict__ src, const int* __restrict__ dst,
                            int* __restrict__ cursor, int* __restrict__ esrc) {
    int e = blockIdx.x * 256 + threadIdx.x;
    if (e < EE) {
        int d = dst[e];
        int idx = atomicAdd(&cursor[d], 1);
        esrc[idx] = src[e];
    }
}

// ---------------- GCN aggregation, optional fused relu / split / f32 outputs ----------------
template<int RELU, int WF32, int WSPLIT>
__global__ __launch_bounds__(256) void gcn_agg(const float* __restrict__ xw, const int* __restrict__ esrc,
        const int* __restrict__ rowstart, const int* __restrict__ cnt, const float* __restrict__ dinv,
        const float* __restrict__ bias, float* __restrict__ out,
        u16* __restrict__ ohi, u16* __restrict__ olo) {
    int wave = threadIdx.x >> 6, lane = threadIdx.x & 63;
    int d = blockIdx.x * 4 + wave;
    if (d >= NN) return;
    int start = rowstart[d];
    int len = cnt[d];
    float dd = dinv[d];
    int h = lane * 4;
    float4 a = *(const float4*)&xw[(size_t)d * HIDD + h];
    float4 acc;
    acc.x = a.x * dd; acc.y = a.y * dd; acc.z = a.z * dd; acc.w = a.w * dd;
    for (int i = 0; i < len; i++) {
        int s = esrc[start + i];
        float ds = dinv[s];
        float4 b = *(const float4*)&xw[(size_t)s * HIDD + h];
        acc.x = fmaf(b.x, ds, acc.x);
        acc.y = fmaf(b.y, ds, acc.y);
        acc.z = fmaf(b.z, ds, acc.z);
        acc.w = fmaf(b.w, ds, acc.w);
    }
    float o0 = acc.x * dd + bias[h + 0];
    float o1 = acc.y * dd + bias[h + 1];
    float o2 = acc.z * dd + bias[h + 2];
    float o3 = acc.w * dd + bias[h + 3];
    if (RELU) {
        o0 = fmaxf(o0, 0.f); o1 = fmaxf(o1, 0.f); o2 = fmaxf(o2, 0.f); o3 = fmaxf(o3, 0.f);
    }
    if (WF32) {
        float4 o; o.x = o0; o.y = o1; o.z = o2; o.w = o3;
        *(float4*)&out[(size_t)d * HIDD + h] = o;
    }
    if (WSPLIT) {
        ushort4 hv, lv;
        u16 h0 = f2bf(o0), h1 = f2bf(o1), h2 = f2bf(o2), h3 = f2bf(o3);
        hv.x = h0; hv.y = h1; hv.z = h2; hv.w = h3;
        lv.x = f2bf(o0 - bf2f(h0)); lv.y = f2bf(o1 - bf2f(h1));
        lv.z = f2bf(o2 - bf2f(h2)); lv.w = f2bf(o3 - bf2f(h3));
        *(ushort4*)&ohi[(size_t)d * HIDD + h] = hv;
        *(ushort4*)&olo[(size_t)d * HIDD + h] = lv;
    }
}

__global__ void mask_kernel(const int* __restrict__ nid, float* __restrict__ x) {
    int node = nid[blockIdx.x];
    x[(size_t)node * HIDD + threadIdx.x] = 0.f;
}

__global__ void bcast_kernel(const float* __restrict__ row, float* __restrict__ out) {
    out[(size_t)blockIdx.x * HIDD + threadIdx.x] = row[threadIdx.x];
}

__global__ void bcast10_kernel(const float* __restrict__ y10, float* __restrict__ out) {
    int i = blockIdx.x * 256 + threadIdx.x;
    if (i < NN * OUTD) out[i] = y10[i % OUTD];
}

// ---------------- splits ----------------
__global__ void split_kernel(const float* __restrict__ x, u16* __restrict__ hi, u16* __restrict__ lo, int n) {
    int i = blockIdx.x * 256 + threadIdx.x;
    if (i < n) {
        float v = x[i];
        u16 h = f2bf(v);
        hi[i] = h;
        lo[i] = f2bf(v - bf2f(h));
    }
}

// W[256,256] -> Bt[256][768] = [Whi^T | Whi^T | Wlo^T], 6 matrices in one launch
__global__ void wsplit_all(const float* __restrict__ w0, const float* __restrict__ w1,
        const float* __restrict__ w2, const float* __restrict__ w3,
        const float* __restrict__ w4, const float* __restrict__ w5, u16* __restrict__ bt) {
    const float* W[6] = { w0, w1, w2, w3, w4, w5 };
    const float* Wm = W[blockIdx.y];
    u16* Bt = bt + (size_t)blockIdx.y * 256 * 768;
    int c = blockIdx.x, k = threadIdx.x;
    float x = Wm[k * 256 + c];
    u16 hi = f2bf(x), lo = f2bf(x - bf2f(hi));
    Bt[c * 768 + k] = hi;
    Bt[c * 768 + 256 + k] = hi;
    Bt[c * 768 + 512 + k] = lo;
}

// ---------------- split-bf16 MFMA GEMM: [R,256(hi)+256(lo)] x Bt[256][768] ----------------
// ACT: 0 none, 1 gelu, 2 tanh. MEAN: fused per-node (8-row) mean epilogue -> split out.
template<int ACT, int WF32, int WSPLIT, int MEAN>
__global__ __launch_bounds__(256) void gemm_split(
        const u16* __restrict__ Ahi, const u16* __restrict__ Alo,
        const u16* __restrict__ Bt, const float* __restrict__ bias,
        float* __restrict__ outf, u16* __restrict__ ohi, u16* __restrict__ olo,
        const float* __restrict__ xsum, int R) {
    __shared__ __align__(16) u16 ldsA[128 * 64];
    __shared__ __align__(16) u16 ldsB[128 * 64];
    int tid = threadIdx.x;
    int lane = tid & 63, w = tid >> 6;
    int rowbase = blockIdx.x * 128;
    int cb = blockIdx.y;
    int wrow = (w >> 1) * 64, wcol = (w & 1) * 64;
    f32x4 acc[4][4];
    #pragma unroll
    for (int i = 0; i < 4; i++)
        #pragma unroll
        for (int j = 0; j < 4; j++) acc[i][j] = f32x4{0.f, 0.f, 0.f, 0.f};

    for (int c = 0; c < 12; c++) {
        const u16* Aseg = (c >= 4 && c < 8) ? Alo : Ahi;
        int koff = (c & 3) * 64;
        __syncthreads();
        #pragma unroll
        for (int i = 0; i < 4; i++) {
            int j = i * 256 + tid;
            int r = j >> 3, sl = j & 7;
            int grow = rowbase + r; if (grow > R - 1) grow = R - 1;
            const u16* gp = Aseg + (size_t)grow * 256 + koff + ((sl ^ (r & 7)) << 3);
            gload16(gp, &ldsA[(i * 256 + (tid & 192)) << 3]);
        }
        #pragma unroll
        for (int i = 0; i < 4; i++) {
            int j = i * 256 + tid;
            int r = j >> 3, sl = j & 7;
            const u16* gp = Bt + (size_t)(cb * 128 + r) * 768 + c * 64 + ((sl ^ (r & 7)) << 3);
            gload16(gp, &ldsB[(i * 256 + (tid & 192)) << 3]);
        }
        __syncthreads();
        #pragma unroll
        for (int ks = 0; ks < 2; ks++) {
            bf16x8 a[4], b[4];
            #pragma unroll
            for (int rf = 0; rf < 4; rf++) {
                int rr = wrow + rf * 16 + (lane & 15);
                int slot = (lane >> 4) + ks * 4;
                a[rf] = *(const bf16x8*)&ldsA[(rr << 6) + ((slot ^ (rr & 7)) << 3)];
            }
            #pragma unroll
            for (int cf = 0; cf < 4; cf++) {
                int cc = wcol + cf * 16 + (lane & 15);
                int slot = (lane >> 4) + ks * 4;
                b[cf] = *(const bf16x8*)&ldsB[(cc << 6) + ((slot ^ (cc & 7)) << 3)];
            }
            #pragma unroll
            for (int rf = 0; rf < 4; rf++)
                #pragma unroll
                for (int cf = 0; cf < 4; cf++)
                    acc[rf][cf] = __builtin_amdgcn_mfma_f32_16x16x32_bf16(a[rf], b[cf], acc[rf][cf], 0, 0, 0);
        }
    }
    #pragma unroll
    for (int rf = 0; rf < 4; rf++) {
        #pragma unroll
        for (int cf = 0; cf < 4; cf++) {
            int col = cb * 128 + wcol + cf * 16 + (lane & 15);
            float bv = bias[col];
            f32x4 v = acc[rf][cf];
            if (MEAN) {
                float s = v[0] + v[1] + v[2] + v[3] + 4.f * bv;
                float o = __shfl_xor(s, 16, 64);
                float nodesum = s + o;
                if (((lane >> 4) & 1) == 0) {
                    int node = ((rowbase + wrow + rf * 16) >> 3) + ((lane >> 4) >> 1);
                    float vv = (xsum[(size_t)node * 256 + col] + nodesum) * 0.125f;
                    u16 hi = f2bf(vv), lo = f2bf(vv - bf2f(hi));
                    ohi[(size_t)node * 256 + col] = hi;
                    olo[(size_t)node * 256 + col] = lo;
                }
            } else {
                int row0 = rowbase + wrow + rf * 16 + ((lane >> 4) << 2);
                #pragma unroll
                for (int r = 0; r < 4; r++) {
                    int row = row0 + r;
                    if (row < R) {
                        float val = v[r] + bv;
                        if (ACT == 1) val = gelu_f(val);
                        if (ACT == 2) val = tanhf(val);
                        if (WF32) outf[(size_t)row * 256 + col] = val;
                        if (WSPLIT) {
                            u16 hi = f2bf(val), lo = f2bf(val - bf2f(hi));
                            ohi[(size_t)row * 256 + col] = hi;
                            olo[(size_t)row * 256 + col] = lo;
                        }
                    }
                }
            }
        }
    }
}

// ---------------- mixer front: window build, LN1, token-mix, residual, LN2, split ----------------
// NOTE: z_hi/z_lo/xsum_out are CHUNK-LOCAL (indexed by blockIdx.x); prev1/prev2 absolute.
__global__ __launch_bounds__(256) void mixer_front(
        const float* __restrict__ prev1, const float* __restrict__ prev2, int nodebase,
        const float* __restrict__ ln1_g, const float* __restrict__ ln1_b,
        const float* __restrict__ tw1, const float* __restrict__ tb1,
        const float* __restrict__ tw2, const float* __restrict__ tb2,
        const float* __restrict__ ln2_g, const float* __restrict__ ln2_b,
        u16* __restrict__ z_hi, u16* __restrict__ z_lo, float* __restrict__ xsum_out) {
    int n = nodebase + blockIdx.x;
    int tid = threadIdx.x;
    int wave = tid >> 6, lane = tid & 63;
    __shared__ __align__(16) float sx[MTOK][HIDD];
    __shared__ float stw1[64], stw2[64], stb1[8], stb2[8];
    __shared__ float red[MTOK][2];
    if (tid < 64) { stw1[tid] = tw1[tid]; stw2[tid] = tw2[tid]; }
    if (tid < 8)  { stb1[tid] = tb1[tid]; stb2[tid] = tb2[tid]; }
    #pragma unroll
    for (int m = 0; m < MTOK; m++) {
        const float* src = (m == MTOK - 1) ? prev1 : (m == MTOK - 2) ? prev2 : nullptr;
        sx[m][tid] = src ? src[(size_t)n * HIDD + tid] : 0.f;
    }
    __syncthreads();
    float g1v = ln1_g[tid], b1v = ln1_b[tid];
    #pragma unroll
    for (int rep = 0; rep < 2; rep++) {
        int m = wave + rep * 4;
        float x0 = sx[m][lane], x1 = sx[m][lane + 64], x2 = sx[m][lane + 128], x3 = sx[m][lane + 192];
        float s = x0 + x1 + x2 + x3;
        float ss = x0 * x0 + x1 * x1 + x2 * x2 + x3 * x3;
        for (int off = 32; off > 0; off >>= 1) { s += __shfl_down(s, off, 64); ss += __shfl_down(ss, off, 64); }
        if (lane == 0) {
            float mu = s * (1.f / HIDD);
            float var = ss * (1.f / HIDD) - mu * mu;
            red[m][0] = mu;
            red[m][1] = rsqrtf(var + LNEPS);
        }
    }
    __syncthreads();
    float ty[MTOK];
    #pragma unroll
    for (int m = 0; m < MTOK; m++) ty[m] = (sx[m][tid] - red[m][0]) * red[m][1] * g1v + b1v;
    float u[MTOK];
    #pragma unroll
    for (int k = 0; k < MTOK; k++) {
        float a = stb1[k];
        #pragma unroll
        for (int m = 0; m < MTOK; m++) a = fmaf(ty[m], stw1[m * MTOK + k], a);
        u[k] = gelu_f(a);
    }
    #pragma unroll
    for (int k = 0; k < MTOK; k++) {
        float a = stb2[k];
        #pragma unroll
        for (int m = 0; m < MTOK; m++) a = fmaf(u[m], stw2[m * MTOK + k], a);
        sx[k][tid] += a;
    }
    __syncthreads();
    float xs = 0.f;
    #pragma unroll
    for (int m = 0; m < MTOK; m++) xs += sx[m][tid];
    xsum_out[(size_t)blockIdx.x * HIDD + tid] = xs;   // chunk-local (fix)
    float g2v = ln2_g[tid], b2v = ln2_b[tid];
    #pragma unroll
    for (int rep = 0; rep < 2; rep++) {
        int m = wave + rep * 4;
        float x0 = sx[m][lane], x1 = sx[m][lane + 64], x2 = sx[m][lane + 128], x3 = sx[m][lane + 192];
        float s = x0 + x1 + x2 + x3;
        float ss = x0 * x0 + x1 * x1 + x2 * x2 + x3 * x3;
        for (int off = 32; off > 0; off >>= 1) { s += __shfl_down(s, off, 64); ss += __shfl_down(ss, off, 64); }
        if (lane == 0) {
            float mu = s * (1.f / HIDD);
            float var = ss * (1.f / HIDD) - mu * mu;
            red[m][0] = mu;
            red[m][1] = rsqrtf(var + LNEPS);
        }
    }
    __syncthreads();
    #pragma unroll
    for (int m = 0; m < MTOK; m++) {
        float z = (sx[m][tid] - red[m][0]) * red[m][1] * g2v + b2v;
        u16 hi = f2bf(z), lo = f2bf(z - bf2f(hi));
        size_t idx = ((size_t)blockIdx.x * MTOK + m) * HIDD + tid;
        z_hi[idx] = hi;
        z_lo[idx] = lo;
    }
}

// ---------------- full f32 mixer for the (uniform) t=0 row ----------------
__global__ __launch_bounds__(256) void mixer_kernel(
        const float* __restrict__ ln1_g, const float* __restrict__ ln1_b,
        const float* __restrict__ tw1, const float* __restrict__ tb1,
        const float* __restrict__ tw2, const float* __restrict__ tb2,
        const float* __restrict__ ln2_g, const float* __restrict__ ln2_b,
        const float* __restrict__ cw1, const float* __restrict__ cb1,
        const float* __restrict__ cw2, const float* __restrict__ cb2,
        float* __restrict__ vout) {
    int tid = threadIdx.x;
    __shared__ __align__(16) float sx[MTOK][HIDD];
    __shared__ __align__(16) float sy[MTOK][HIDD];
    __shared__ float stw1[64], stw2[64], stb1[8], stb2[8];
    if (tid < 64) { stw1[tid] = tw1[tid]; stw2[tid] = tw2[tid]; }
    if (tid < 8)  { stb1[tid] = tb1[tid]; stb2[tid] = tb2[tid]; }
    __syncthreads();
    float b1v = ln1_b[tid];
    float ty[MTOK];
    #pragma unroll
    for (int m = 0; m < MTOK; m++) ty[m] = b1v;
    float u[MTOK];
    #pragma unroll
    for (int k = 0; k < MTOK; k++) {
        float a = stb1[k];
        #pragma unroll
        for (int m = 0; m < MTOK; m++) a = fmaf(ty[m], stw1[m * MTOK + k], a);
        u[k] = gelu_f(a);
    }
    #pragma unroll
    for (int k = 0; k < MTOK; k++) {
        float a = stb2[k];
        #pragma unroll
        for (int m = 0; m < MTOK; m++) a = fmaf(u[m], stw2[m * MTOK + k], a);
        sx[k][tid] = a;
    }
    __syncthreads();
    __shared__ float red[MTOK][2];
    int wave = tid >> 6, lane = tid & 63;
    float g2v = ln2_g[tid], b2v = ln2_b[tid];
    #pragma unroll
    for (int rep = 0; rep < 2; rep++) {
        int m = wave + rep * 4;
        float x0 = sx[m][lane], x1 = sx[m][lane + 64], x2 = sx[m][lane + 128], x3 = sx[m][lane + 192];
        float s = x0 + x1 + x2 + x3;
        float ss = x0 * x0 + x1 * x1 + x2 * x2 + x3 * x3;
        for (int off = 32; off > 0; off >>= 1) { s += __shfl_down(s, off, 64); ss += __shfl_down(ss, off, 64); }
        if (lane == 0) {
            float mu = s * (1.f / HIDD);
            float var = ss * (1.f / HIDD) - mu * mu;
            red[m][0] = mu;
            red[m][1] = rsqrtf(var + LNEPS);
        }
    }
    __syncthreads();
    #pragma unroll
    for (int m = 0; m < MTOK; m++) sy[m][tid] = (sx[m][tid] - red[m][0]) * red[m][1] * g2v + b2v;
    __syncthreads();
    float acc[MTOK];
    #pragma unroll
    for (int m = 0; m < MTOK; m++) acc[m] = 0.f;
    for (int h = 0; h < HIDD; h += 4) {
        float w0 = cw1[(h + 0) * HIDD + tid];
        float w1 = cw1[(h + 1) * HIDD + tid];
        float w2 = cw1[(h + 2) * HIDD + tid];
        float w3 = cw1[(h + 3) * HIDD + tid];
        #pragma unroll
        for (int m = 0; m < MTOK; m++) {
            const float4 a = *(const float4*)&sy[m][h];
            acc[m] = fmaf(a.x, w0, acc[m]);
            acc[m] = fmaf(a.y, w1, acc[m]);
            acc[m] = fmaf(a.z, w2, acc[m]);
            acc[m] = fmaf(a.w, w3, acc[m]);
        }
    }
    __syncthreads();
    float cb1v = cb1[tid];
    #pragma unroll
    for (int m = 0; m < MTOK; m++) sy[m][tid] = gelu_f(acc[m] + cb1v);
    __syncthreads();
    float acc2[MTOK];
    #pragma unroll
    for (int m = 0; m < MTOK; m++) acc2[m] = 0.f;
    for (int h = 0; h < HIDD; h += 4) {
        float w0 = cw2[(h + 0) * HIDD + tid];
        float w1 = cw2[(h + 1) * HIDD + tid];
        float w2 = cw2[(h + 2) * HIDD + tid];
        float w3 = cw2[(h + 3) * HIDD + tid];
        #pragma unroll
        for (int m = 0; m < MTOK; m++) {
            const float4 a = *(const float4*)&sy[m][h];
            acc2[m] = fmaf(a.x, w0, acc2[m]);
            acc2[m] = fmaf(a.y, w1, acc2[m]);
            acc2[m] = fmaf(a.z, w2, acc2[m]);
            acc2[m] = fmaf(a.w, w3, acc2[m]);
        }
    }
    float cb2v = cb2[tid];
    float ssum = 0.f;
    #pragma unroll
    for (int m = 0; m < MTOK; m++) ssum += sx[m][tid] + acc2[m] + cb2v;
    vout[tid] = ssum * (1.f / MTOK);
}

// ---------------- single-row head kernels (t=0 path) ----------------
template<int ACT>
__global__ __launch_bounds__(256) void rowgemm_kernel(const float* __restrict__ in_row,
        const float* __restrict__ Wm, const float* __restrict__ b, float* __restrict__ out_row) {
    __shared__ float s[HIDD];
    int tid = threadIdx.x;
    s[tid] = in_row[tid];
    __syncthreads();
    float acc = 0.f;
    for (int k = 0; k < HIDD; k++) acc = fmaf(s[k], Wm[k * HIDD + tid], acc);
    float v = acc + b[tid];
    if (ACT == 2) v = tanhf(v);
    out_row[tid] = v;
}

__global__ __launch_bounds__(256) void rowcls2_kernel(const float* __restrict__ g1row,
        const float* __restrict__ wm, const float* __restrict__ b, float* __restrict__ y10) {
    __shared__ float s[HIDD];
    int tid = threadIdx.x;
    s[tid] = g1row[tid];
    __syncthreads();
    if (tid < OUTD) {
        float a = 0.f;
        for (int h = 0; h < HIDD; h++) a = fmaf(s[h], wm[h * OUTD + tid], a);
        y10[tid] = fmaxf(a + b[tid], 0.f);
    }
}

// ---------------- cls2 for the big rows ----------------
__global__ __launch_bounds__(256) void cls2_kernel(const float* __restrict__ g1, const float* __restrict__ wm,
        const float* __restrict__ b, float* __restrict__ out, int rows) {
    __shared__ float sw[HIDD][12];
    int tid = threadIdx.x;
    for (int i = tid; i < HIDD * OUTD; i += 256) sw[i / OUTD][i % OUTD] = wm[i];
    __syncthreads();
    int rl = tid >> 4, kk = tid & 15;
    int r = blockIdx.x * 16 + rl;
    if (r < rows && kk < OUTD) {
        float acc = 0.f;
        const float* grow = g1 + (size_t)r * HIDD;
        for (int h = 0; h < HIDD; h++) acc = fmaf(grow[h], sw[h][kk], acc);
        out[(size_t)r * OUTD + kk] = fmaxf(acc + b[kk], 0.f);
    }
}

extern "C" void kernel_launch(void* const* d_in, const int* in_sizes, int n_in,
                              void* d_out, int out_size, void* d_ws, size_t ws_size,
                              hipStream_t stream) {
    const int* edge    = (const int*)d_in[0];
    const int* node_t  = (const int*)d_in[1];
    const float* emb   = (const float*)d_in[3];
    const float* gcn_w1 = (const float*)d_in[4];
    const float* gcn_b1 = (const float*)d_in[5];
    const float* gcn_w2 = (const float*)d_in[6];
    const float* gcn_b2 = (const float*)d_in[7];
    const float* ln1_g = (const float*)d_in[8];
    const float* ln1_b = (const float*)d_in[9];
    const float* tw1   = (const float*)d_in[10];
    const float* tb1   = (const float*)d_in[11];
    const float* tw2   = (const float*)d_in[12];
    const float* tb2   = (const float*)d_in[13];
    const float* ln2_g = (const float*)d_in[14];
    const float* ln2_b = (const float*)d_in[15];
    const float* cw1   = (const float*)d_in[16];
    const float* cb1   = (const float*)d_in[17];
    const float* cw2   = (const float*)d_in[18];
    const float* cb2   = (const float*)d_in[19];
    const float* pred_w = (const float*)d_in[20];
    const float* pred_b = (const float*)d_in[21];
    const float* cls1_w = (const float*)d_in[22];
    const float* cls1_b = (const float*)d_in[23];
    const float* cls2_w = (const float*)d_in[24];
    const float* cls2_b = (const float*)d_in[25];

    char* wsb = (char*)d_ws;
    size_t off = 0;
    auto alloc = [&](size_t bytes) { char* p = wsb + off; off = (off + bytes + 255) & ~(size_t)255; return p; };
    // fixed buffers
    float* xsum = (float*)alloc((size_t)NN * HIDD * 4);
    u16* v_hi  = (u16*)alloc((size_t)NN * HIDD * 2);
    u16* v_lo  = (u16*)alloc((size_t)NN * HIDD * 2);
    u16* h_hi  = (u16*)alloc((size_t)2 * NN * HIDD * 2);
    u16* h_lo  = (u16*)alloc((size_t)2 * NN * HIDD * 2);
    float* xs0 = (float*)alloc((size_t)NN * HIDD * 4);
    float* xs1 = (float*)alloc((size_t)NN * HIDD * 4);
    float* xw  = (float*)alloc((size_t)NN * HIDD * 4);   // also g1 alias (head)
    float* xw2 = (float*)alloc((size_t)NN * HIDD * 4);
    u16* emb_hi = (u16*)alloc((size_t)NN * HIDD * 2);
    u16* emb_lo = (u16*)alloc((size_t)NN * HIDD * 2);
    u16* agg_hi = (u16*)alloc((size_t)NN * HIDD * 2);
    u16* agg_lo = (u16*)alloc((size_t)NN * HIDD * 2);
    u16* Bt_all = (u16*)alloc((size_t)6 * 256 * 768 * 2);
    u16* Bt_cw1  = Bt_all;
    u16* Bt_cw2  = Bt_all + 1 * 256 * 768;
    u16* Bt_pred = Bt_all + 2 * 256 * 768;
    u16* Bt_cls1 = Bt_all + 3 * 256 * 768;
    u16* Bt_gw1  = Bt_all + 4 * 256 * 768;
    u16* Bt_gw2  = Bt_all + 5 * 256 * 768;
    float* dinv  = (float*)alloc(NN * 4);
    float* zeros = (float*)alloc(HIDD * 4);
    float* v0row = (float*)alloc(HIDD * 4);
    float* h0row = (float*)alloc(HIDD * 4);
    float* g1row = (float*)alloc(HIDD * 4);
    float* y0row = (float*)alloc(16 * 4);
    int* cnt    = (int*)alloc(NN * 4);
    int* rowst  = (int*)alloc(NN * 4);
    int* cursor = (int*)alloc(NN * 4);
    int* esrc   = (int*)alloc(EE * 4);
    // g1 (head scratch, 2*N*H f32) aliases xw+xw2 (both dead before head)
    float* g1 = xw;
    // z buffers from remaining workspace (4 bufs x CHN*8*256 u16 = CHN*16384 B)
    size_t remain = (ws_size > off + 4096) ? (ws_size - off - 4096) : 0;
    int CHN = (int)(remain / 16384);
    if (CHN > NN) CHN = NN;
    CHN &= ~15;
    if (CHN < 16) CHN = 16;
    const size_t ZE = (size_t)CHN * MTOK * HIDD;
    u16* z_hi  = (u16*)alloc(ZE * 2);
    u16* z_lo  = (u16*)alloc(ZE * 2);
    u16* z2_hi = (u16*)alloc(ZE * 2);
    u16* z2_lo = (u16*)alloc(ZE * 2);

    float* h_out = (float*)d_out;                    // [3*N*256]
    float* y_out = h_out + (size_t)TT * NN * HIDD;   // [3*N*10]

    float* xs_arr[2] = { xs0, xs1 };

    // one-time prep
    hipMemsetAsync(zeros, 0, HIDD * sizeof(float), stream);
    wsplit_all<<<dim3(256, 6), 256, 0, stream>>>(cw1, cw2, pred_w, cls1_w, gcn_w1, gcn_w2, Bt_all);
    split_kernel<<<(NN * HIDD + 255) / 256, 256, 0, stream>>>(emb, emb_hi, emb_lo, NN * HIDD);
    // xw = emb @ gcn_w1 (t-invariant)
    gemm_split<0, 1, 0, 0><<<dim3((NN + 127) / 128, 2), 256, 0, stream>>>(
        emb_hi, emb_lo, Bt_gw1, zeros, xw, nullptr, nullptr, nullptr, NN);

    for (int t = 0; t < TT; t++) {
        if (t == 0) {
            mixer_kernel<<<1, 256, 0, stream>>>(ln1_g, ln1_b, tw1, tb1, tw2, tb2,
                ln2_g, ln2_b, cw1, cb1, cw2, cb2, v0row);
            rowgemm_kernel<2><<<1, 256, 0, stream>>>(v0row, pred_w, pred_b, h0row);
            bcast_kernel<<<NN, 256, 0, stream>>>(h0row, h_out);
            rowgemm_kernel<0><<<1, 256, 0, stream>>>(h0row, cls1_w, cls1_b, g1row);
            rowcls2_kernel<<<1, 256, 0, stream>>>(g1row, cls2_w, cls2_b, y0row);
            bcast10_kernel<<<(NN * OUTD + 255) / 256, 256, 0, stream>>>(y0row, y_out);
        } else {
            const float* prev1 = xs_arr[(t - 1) & 1];
            const float* prev2 = (t >= 2) ? xs_arr[(t - 2) & 1] : nullptr;
            for (int nb = 0; nb < NN; nb += CHN) {
                int nodes = NN - nb < CHN ? NN - nb : CHN;
                int R = nodes * MTOK;
                int rb = R / 128;
                mixer_front<<<nodes, 256, 0, stream>>>(prev1, prev2, nb,
                    ln1_g, ln1_b, tw1, tb1, tw2, tb2, ln2_g, ln2_b, z_hi, z_lo, xsum);
                gemm_split<1, 0, 1, 0><<<dim3(rb, 2), 256, 0, stream>>>(
                    z_hi, z_lo, Bt_cw1, cb1, nullptr, z2_hi, z2_lo, nullptr, R);
                gemm_split<0, 0, 1, 1><<<dim3(rb, 2), 256, 0, stream>>>(
                    z2_hi, z2_lo, Bt_cw2, cb2, nullptr,
                    v_hi + (size_t)nb * HIDD, v_lo + (size_t)nb * HIDD,
                    xsum, R);
            }
            gemm_split<2, 1, 1, 0><<<dim3((NN + 127) / 128, 2), 256, 0, stream>>>(
                v_hi, v_lo, Bt_pred, pred_b,
                h_out + (size_t)t * NN * HIDD,
                h_hi + (size_t)(t - 1) * NN * HIDD, h_lo + (size_t)(t - 1) * NN * HIDD, nullptr, NN);
        }
        if (t < TT - 1) {
            const int* src = edge + (size_t)t * 2 * EE;
            const int* dst = src + EE;
            hipMemsetAsync(cnt, 0, NN * sizeof(int), stream);
            count_kernel<<<(EE + 255) / 256, 256, 0, stream>>>(dst, cnt);
            scan_kernel<<<1, 1024, 0, stream>>>(cnt, rowst, cursor, dinv);
            fill_kernel<<<(EE + 255) / 256, 256, 0, stream>>>(src, dst, cursor, esrc);
            // layer 1 aggregation: relu + split epilogue
            gcn_agg<1, 0, 1><<<(NN + 3) / 4, 256, 0, stream>>>(xw, esrc, rowst, cnt, dinv,
                gcn_b1, nullptr, agg_hi, agg_lo);
            // layer 2 transform + aggregation
            gemm_split<0, 1, 0, 0><<<dim3((NN + 127) / 128, 2), 256, 0, stream>>>(
                agg_hi, agg_lo, Bt_gw2, zeros, xw2, nullptr, nullptr, nullptr, NN);
            gcn_agg<0, 1, 0><<<(NN + 3) / 4, 256, 0, stream>>>(xw2, esrc, rowst, cnt, dinv,
                gcn_b2, xs_arr[t & 1], nullptr, nullptr);
            mask_kernel<<<AA, 256, 0, stream>>>(node_t + (size_t)t * AA, xs_arr[t & 1]);
        }
    }
    // head for t=1,2 rows
    gemm_split<0, 1, 0, 0><<<dim3((2 * NN + 127) / 128, 2), 256, 0, stream>>>(
        h_hi, h_lo, Bt_cls1, cls1_b, g1, nullptr, nullptr, nullptr, 2 * NN);
    cls2_kernel<<<(2 * NN + 15) / 16, 256, 0, stream>>>(g1, cls2_w, cls2_b, y_out + (size_t)NN * OUTD, 2 * NN);
}